// Round 6
// baseline (273.385 us; speedup 1.0000x reference)
//
#include <hip/hip_runtime.h>
#include <hip/hip_bf16.h>
#include <stdint.h>

// B=32768, D=1024, T=8, O=128, DEPTH=6 -> 512 padded node cols (8 trees x 64)
#define KDIM 1024
#define TSTR 72            // tree stride in st (shorts)
#define RSTR 576           // row stride in st (shorts)

typedef __attribute__((ext_vector_type(4))) float f32x4;
typedef __attribute__((ext_vector_type(8))) short bf16x8;

// ws: wb [32 ks][512 n][32 kl] bf16 = 1 MiB @0 ; lb [16 kq][128 o][32] bf16 = 128 KiB @1 MiB
#define WS_LB_OFF ((size_t)1 << 20)

__device__ __forceinline__ unsigned short f2bf_rne(float f) {
    unsigned u = __float_as_uint(f);
    u = (u + 0x7fffu + ((u >> 16) & 1u)) >> 16;
    return (unsigned short)u;
}

__device__ __forceinline__ unsigned int pack2_bf16(float a, float b) {
    __hip_bfloat162 h = __float22bfloat162_rn(make_float2(a, b));
    union { __hip_bfloat162 h; unsigned int u; } cv;
    cv.h = h;
    return cv.u;   // a low 16, b high
}

__device__ __forceinline__ float gs_get(const uint4* q, int i) {
    uint4 v = q[i >> 3];
    int c = (i >> 1) & 3;
    unsigned w = (c == 0) ? v.x : (c == 1) ? v.y : (c == 2) ? v.z : v.w;
    return __uint_as_float((i & 1) ? (w & 0xffff0000u) : (w << 16));
}

// ---- prep: node weights -> bf16 [ks][n][32], chunk swizzle cp^(n&3) (VERBATIM R2) ----
__global__ void prep_w(const float* __restrict__ nw, unsigned short* __restrict__ wb) {
    int idx = blockIdx.x * 256 + threadIdx.x;       // 524288
    int kl = idx & 31;
    int n  = (idx >> 5) & 511;
    int ks = idx >> 14;
    int cp = kl >> 3, e = kl & 7;
    int kchunk = cp ^ (n & 3);
    int d = ks * 32 + kchunk * 8 + e;
    int t = n >> 6, i = n & 63;
    float v = (i < 63) ? nw[(t * KDIM + d) * 63 + i] : 0.0f;
    wb[idx] = f2bf_rne(v);
}

// ---- prep: leaf weights -> bf16 [kq][o][32] (VERBATIM R2) ----
__global__ void prep_l(const float* __restrict__ lw, unsigned short* __restrict__ lb) {
    int idx = blockIdx.x * 256 + threadIdx.x;       // 65536
    int kk = idx & 31;
    int o  = (idx >> 5) & 127;
    int kq = idx >> 12;
    int c = kq * 32 + kk;                           // t*64 + l
    int t = c >> 6, l = c & 63;
    lb[idx] = f2bf_rne(lw[(t * 128 + o) * 64 + l]);
}

// ---- fused: s = smooth_step(x@W) -> tree scan -> out = mu@L ----
// RACE-HARDENED baseline: no global_load_lds (VGPR staging), no LDS union,
// threadfence before k-loop barriers. 32 rows/block, 256 thr, BK=32.
__launch_bounds__(256, 2)
__global__ void fused(const float* __restrict__ x, const unsigned short* __restrict__ wb,
                      const unsigned short* __restrict__ lb, float* __restrict__ out) {
    __shared__ __align__(16) unsigned short xs[32 * 40];     //  2,560 B
    __shared__ __align__(16) unsigned short wl[512 * 32];    // 32,768 B
    __shared__ __align__(16) unsigned short st[32 * RSTR];   // 36,864 B  (separate: no union)

    const int tid  = threadIdx.x;
    const int wave = tid >> 6, lane = tid & 63;
    const int quad = lane >> 4, l16 = lane & 15;
    const int mb   = blockIdx.x;           // 1024 blocks x 32 rows

    f32x4 acc[8][2];                       // [ct][rt]
    const f32x4 z4 = {0.f, 0.f, 0.f, 0.f};
    #pragma unroll
    for (int a = 0; a < 8; ++a) { acc[a][0] = z4; acc[a][1] = z4; }

    const int xrow = tid >> 3, xq8 = tid & 7;
    const float* xg0 = x + (size_t)(mb * 32 + xrow) * KDIM + xq8 * 4;

    for (int ks = 0; ks < 32; ++ks) {
        __threadfence_block();
        __syncthreads();                   // A: prior iter's fragment reads done everywhere
        // stage W: 32 KB via VGPR round-trip (2 chunks of 4x16B per thread)
        const unsigned short* wks = wb + (size_t)ks * (512 * 32);
        #pragma unroll
        for (int h = 0; h < 2; ++h) {
            uint4 wv[4];
            #pragma unroll
            for (int it = 0; it < 4; ++it)
                wv[it] = *(const uint4*)(wks + (size_t)((h * 4 + it) * 256 + tid) * 8);
            #pragma unroll
            for (int it = 0; it < 4; ++it)
                *(uint4*)&wl[((h * 4 + it) * 256 + tid) * 8] = wv[it];
        }
        // stage x: 4 fp32 -> 4 bf16 -> 1 ds_write_b64 per thread
        {
            float4 f0 = *(const float4*)(xg0 + ks * 32);
            uint2 pk;
            pk.x = pack2_bf16(f0.x, f0.y);
            pk.y = pack2_bf16(f0.z, f0.w);
            *(uint2*)&xs[xrow * 40 + xq8 * 4] = pk;
        }
        __threadfence_block();
        __syncthreads();                   // B: all staging visible
        // fragments + 16 MFMA  [VERBATIM R2/R5 column path]
        bf16x8 af[8], bfr[2];
        #pragma unroll
        for (int ct = 0; ct < 8; ++ct) {
            int col = wave * 128 + ct * 16 + l16;
            int chunk = quad ^ (col & 3);
            af[ct] = *(const bf16x8*)&wl[col * 32 + chunk * 8];
        }
        #pragma unroll
        for (int rt = 0; rt < 2; ++rt)
            bfr[rt] = *(const bf16x8*)&xs[(rt * 16 + l16) * 40 + quad * 8];
        #pragma unroll
        for (int ct = 0; ct < 8; ++ct)
            #pragma unroll
            for (int rt = 0; rt < 2; ++rt)
                acc[ct][rt] = __builtin_amdgcn_mfma_f32_16x16x32_bf16(af[ct], bfr[rt], acc[ct][rt], 0, 0, 0);
    }

    __threadfence_block();
    __syncthreads();
    // epilogue: smooth_step, s -> st  [VERBATIM R5]
    #pragma unroll
    for (int rt2 = 0; rt2 < 2; ++rt2) {
        int row = rt2 * 16 + l16;
        #pragma unroll
        for (int ct = 0; ct < 8; ++ct) {
            int colb = wave * 128 + ct * 16 + quad * 4;
            f32x4 a = acc[ct][rt2];
            float s0[4];
            #pragma unroll
            for (int j = 0; j < 4; ++j) {
                float u = a[j];
                u = fminf(fmaxf(u, -0.5f), 0.5f);
                s0[j] = u * (1.5f - 2.0f * u * u) + 0.5f;
            }
            uint2 pk;
            pk.x = pack2_bf16(s0[0], s0[1]);
            pk.y = pack2_bf16(s0[2], s0[3]);
            *(uint2*)&st[row * RSTR + (colb >> 6) * TSTR + (colb & 63)] = pk;
        }
    }
    __syncthreads();
    // scan: one (row, tree) per thread, in place s -> mu  [VERBATIM R5]
    {
        int r = tid >> 3, t = tid & 7;
        unsigned short* base = &st[r * RSTR + t * TSTR];
        uint4 q[8];
        #pragma unroll
        for (int c = 0; c < 8; ++c) q[c] = *(const uint4*)(base + c * 8);
        float mu[32];
        mu[0] = 1.0f;
        int start = 0;
        #pragma unroll
        for (int lvl = 0; lvl < 5; ++lvl) {
            int width = 1 << lvl;
            #pragma unroll
            for (int j = width - 1; j >= 0; --j) {
                float m = mu[j], s_ = gs_get(q, start + j);
                mu[2 * j + 1] = m * (1.0f - s_);
                mu[2 * j]     = m * s_;
            }
            start += width;
        }
        #pragma unroll
        for (int c = 0; c < 8; ++c) {               // level 5 fused with pack+store
            unsigned pk2[4];
            #pragma unroll
            for (int e = 0; e < 4; ++e) {
                int j = c * 4 + e;
                float m = mu[j], s_ = gs_get(q, 31 + j);
                pk2[e] = pack2_bf16(m * s_, m * (1.0f - s_));
            }
            uint4 v; v.x = pk2[0]; v.y = pk2[1]; v.z = pk2[2]; v.w = pk2[3];
            *(uint4*)(base + c * 8) = v;
        }
    }
    __syncthreads();
    // GEMM2: A = leaf (global, L2-hot), B = mu (LDS)  [VERBATIM R5]
    {
        int rtile = wave & 1, ob = (wave >> 1) * 64;
        f32x4 a2[4];
        a2[0] = z4; a2[1] = z4; a2[2] = z4; a2[3] = z4;
        #pragma unroll
        for (int kq = 0; kq < 16; ++kq) {
            int c0 = kq * 32 + quad * 8;
            bf16x8 bmu = *(const bf16x8*)&st[(rtile * 16 + l16) * RSTR + (c0 >> 6) * TSTR + (c0 & 63)];
            #pragma unroll
            for (int ct = 0; ct < 4; ++ct) {
                int o = ob + ct * 16 + l16;
                bf16x8 alf = *(const bf16x8*)(lb + (size_t)(kq * 128 + o) * 32 + quad * 8);
                a2[ct] = __builtin_amdgcn_mfma_f32_16x16x32_bf16(alf, bmu, a2[ct], 0, 0, 0);
            }
        }
        #pragma unroll
        for (int ct = 0; ct < 4; ++ct) {
            int rowg = mb * 32 + rtile * 16 + l16;
            int og = ob + ct * 16 + quad * 4;
            *(f32x4*)(out + (size_t)rowg * 128 + og) = a2[ct];
        }
    }
}

extern "C" void kernel_launch(void* const* d_in, const int* in_sizes, int n_in,
                              void* d_out, int out_size, void* d_ws, size_t ws_size,
                              hipStream_t stream) {
    const float* x  = (const float*)d_in[0];
    const float* nw = (const float*)d_in[1];
    const float* lw = (const float*)d_in[2];
    float* out = (float*)d_out;

    unsigned short* wb = (unsigned short*)d_ws;
    unsigned short* lb = (unsigned short*)((char*)d_ws + WS_LB_OFF);

    prep_w<<<2048, 256, 0, stream>>>(nw, wb);
    prep_l<<<256, 256, 0, stream>>>(lw, lb);
    fused<<<1024, 256, 0, stream>>>(x, wb, lb, out);
}